// Round 10
// baseline (762.490 us; speedup 1.0000x reference)
//
#include <hip/hip_runtime.h>
#include <hip/hip_bf16.h>

// ---------------------------------------------------------------------------
// 2-layer GraphSAGE (mean aggr) on gfx950.
// R13 (this round): barrier-free GEMM. R9's gemm was LDS/barrier-bound
// (48KB LDS reads/kk = 576 cyc/CU vs 160 cyc MFMA/SIMD; vmcnt(0) drain per
// kk serializes A staging latency). New gemm: NO LDS, NO barriers — A and B
// fragments loaded directly to registers. B uses a new Wt layout [kk][q][n]
// (16B chunks) emitted by prep_w -> 4x256B segments per load, L1/L2-hot
// (W = 256KB resident). A = block-private rows streamed from HBM (same
// bytes as staged version). Compiler pipelines freely without barriers.
// Roofline ~30us/gemm (HBM 150-200MB); was ~80us.
// Also: hist_csr fuses node_hist_scan + csr_write (one ebuf pass saved).
// R5-R7: sage_agg at ~3.9 TB/s L2-fill ceiling; FETCH 379 MB ~= 95% of
// structural minimum -> closed. CSR build deterministic (R3).
// NOT included: R10 prep_bin_gather mega-kernel (3x container failures,
// never measured; R9 base passed 2x -> abandoned).
// ---------------------------------------------------------------------------

typedef __bf16 bf16x8 __attribute__((ext_vector_type(8)));
typedef __bf16 bf16x4 __attribute__((ext_vector_type(4)));
typedef float  f32x4  __attribute__((ext_vector_type(4)));
typedef float  f32x8  __attribute__((ext_vector_type(8)));

#define ROWB 1024   // bytes per A row: 512 bf16 (K = 512 = [mean | x])
#define NPART 256   // partition blocks
#define MAXBUK 2048 // bucket capacity bound (N<=131072)

// ---- CSR build ------------------------------------------------------------

// block p: LDS histogram of dst>>6 over its chunk -> hmat[p][:]
__global__ void bin_count(const int* __restrict__ dst, int* __restrict__ hmat,
                          int E, int chunk, int nbuk) {
  __shared__ int lh[MAXBUK];
  int p = blockIdx.x, tid = threadIdx.x;
  for (int i = tid; i < nbuk; i += 256) lh[i] = 0;
  __syncthreads();
  int base = p * chunk, end = min(base + chunk, E);
  for (int e = base + tid; e < end; e += 256) atomicAdd(&lh[dst[e] >> 6], 1);
  __syncthreads();
  for (int i = tid; i < nbuk; i += 256) hmat[p * nbuk + i] = lh[i];
}

// block b: exclusive scan of hmat[0..NPART-1][b]; btot[b] = total
__global__ void col_scan(int* __restrict__ hmat, int* __restrict__ btot, int nbuk) {
  __shared__ int s[NPART];
  int b = blockIdx.x, t = threadIdx.x;  // NPART threads
  int v = hmat[t * nbuk + b];
  s[t] = v; __syncthreads();
  for (int d = 1; d < NPART; d <<= 1) {
    int add = (t >= d) ? s[t - d] : 0;
    __syncthreads();
    s[t] += add;
    __syncthreads();
  }
  hmat[t * nbuk + b] = s[t] - v;  // exclusive within bucket
  if (t == NPART - 1) btot[b] = s[t];
}

// single block, 1024 threads, nb <= 2048: exclusive scan btot -> boff
__global__ void bucket_scan(const int* __restrict__ btot, int* __restrict__ boff, int nb) {
  __shared__ int s[2048];
  int t = threadIdx.x;
  for (int i = t; i < 2048; i += 1024) s[i] = (i < nb) ? btot[i] : 0;
  __syncthreads();
  for (int d = 1; d < 2048; d <<= 1) {
    int v0 = (t >= d) ? s[t - d] : 0;
    int v1 = (t + 1024 >= d) ? s[t + 1024 - d] : 0;
    __syncthreads();
    s[t] += v0; s[t + 1024] += v1;
    __syncthreads();
  }
  for (int i = t; i < nb; i += 1024) boff[i] = s[i] - btot[i];
}

// block p: write its chunk's edges into disjoint per-bucket windows.
// entry = src | ((dst&63) << 18)   (src < 2^18)
__global__ void part_write(const int* __restrict__ src, const int* __restrict__ dst,
                           const int* __restrict__ hmat, const int* __restrict__ boff,
                           int* __restrict__ ebuf, int E, int chunk, int nbuk) {
  __shared__ int cur[MAXBUK];
  int p = blockIdx.x, tid = threadIdx.x;
  for (int i = tid; i < nbuk; i += 256) cur[i] = hmat[p * nbuk + i] + boff[i];
  __syncthreads();
  int base = p * chunk, end = min(base + chunk, E);
  for (int e = base + tid; e < end; e += 256) {
    int d = dst[e];
    int pos = atomicAdd(&cur[d >> 6], 1);  // LDS atomic, low contention
    ebuf[pos] = src[e] | ((d & 63) << 18);
  }
}

// block b: degree hist + in-bucket exclusive scan -> cnt/offs, then place
// the bucket's edges into csr via LDS cursors (fused; one ebuf pass saved,
// second pass reads the bucket window L2-hot).
__global__ void hist_csr(const int* __restrict__ ebuf, const int* __restrict__ boff,
                         const int* __restrict__ btot, int* __restrict__ cnt,
                         int* __restrict__ offs, int* __restrict__ csr, int N) {
  __shared__ int lh[64];
  __shared__ int cur[64];
  int b = blockIdx.x, tid = threadIdx.x;
  if (tid < 64) lh[tid] = 0;
  __syncthreads();
  int s0 = boff[b], s1 = s0 + btot[b];
  for (int i = s0 + tid; i < s1; i += 256) atomicAdd(&lh[ebuf[i] >> 18], 1);
  __syncthreads();
  if (tid < 64) {  // wave 0: 64-wide inclusive shfl scan
    int v = lh[tid];
    int x = v;
#pragma unroll
    for (int d = 1; d < 64; d <<= 1) {
      int y = __shfl_up(x, d);
      if (tid >= d) x += y;
    }
    int o = s0 + x - v;  // exclusive start
    cur[tid] = o;
    int node = b * 64 + tid;
    if (node < N) { cnt[node] = v; offs[node] = o; }
  }
  __syncthreads();
  for (int i = s0 + tid; i < s1; i += 256) {
    int e = ebuf[i];
    int p = atomicAdd(&cur[e >> 18], 1);
    csr[p] = e & 0x3FFFF;
  }
}

// ---- feature prep ---------------------------------------------------------

// B-operand layout for the direct-load GEMM: WtB 16B-chunk index
// c = (kk*4 + q)*256 + n  holds  W[k = kk*32 + q*8 + e][n], e = 0..7.
// (k<256 -> Wl, else Wr at k-256; W* are [k][n] row-major fp32.)
__global__ void prep_w_kernel(const float* __restrict__ W1l, const float* __restrict__ W1r,
                              const float* __restrict__ W2l, const float* __restrict__ W2r,
                              __bf16* __restrict__ Wt1, __bf16* __restrict__ Wt2) {
  int idx = blockIdx.x * 256 + threadIdx.x;  // 0 .. 2*131072-1
  int which = idx >> 17;
  int j = idx & 131071;          // element index in WtB
  int kkq = j >> 11;             // (kk*4+q), 0..63
  int n = (j >> 3) & 255;
  int e = j & 7;
  int k = (kkq >> 2) * 32 + (kkq & 3) * 8 + e;
  const float* Wl = which ? W2l : W1l;
  const float* Wr = which ? W2r : W1r;
  float v = (k < 256) ? Wl[k * 256 + n] : Wr[(k - 256) * 256 + n];
  (which ? Wt2 : Wt1)[j] = (__bf16)v;
}

// x-half gather: xbase points at (row stride ROWB) destination of the x slot
__global__ void gather_x_kernel(const float* __restrict__ emb, const int* __restrict__ x_idx,
                                char* __restrict__ xbase, int N) {
  int wave = threadIdx.x >> 6, lane = threadIdx.x & 63;
  int i = blockIdx.x * 4 + wave;
  if (i >= N) return;
  int s = x_idx[i];
  float4 v = *(const float4*)(emb + (size_t)s * 256 + lane * 4);
  bf16x4 o = { (__bf16)v.x, (__bf16)v.y, (__bf16)v.z, (__bf16)v.w };
  *(bf16x4*)(xbase + (size_t)i * ROWB + lane * 8) = o;
}

// ---- mean aggregation -----------------------------------------------------
// Wave per node; 2x32-lane halves read DIFFERENT src rows at 16B/lane
// (dwordx4). 8 edges/iter, 4 loads in flight. shfl_down(32) combine.
// Perf-equal across MLP 1/2/4 variants -> L2-fill throughput ceiling.

__global__ void sage_agg(const char* __restrict__ srcbase,  // row r: srcbase + r*ROWB, 256 bf16
                         char* __restrict__ dstbase,        // node i: dstbase + i*ROWB, 256 bf16
                         const int* __restrict__ csr, const int* __restrict__ cnt,
                         const int* __restrict__ offs, int N) {
  int wave = threadIdx.x >> 6, lane = threadIdx.x & 63;
  int i = blockIdx.x * 4 + wave;
  if (i >= N) return;
  int deg = cnt[i];
  const int* lp = csr + offs[i];
  int half = lane >> 5, l5 = lane & 31;
  const char* sb = srcbase + l5 * 16;

  f32x8 acc = (f32x8)0.f;
  int g8 = deg >> 3;
  for (int t = 0; t < g8; ++t) {  // 8 edges per iteration (4 per half)
    const int* p = lp + t * 8 + half;
    int s0 = p[0], s1 = p[2], s2 = p[4], s3 = p[6];
    bf16x8 v0 = *(const bf16x8*)(sb + (size_t)s0 * ROWB);
    bf16x8 v1 = *(const bf16x8*)(sb + (size_t)s1 * ROWB);
    bf16x8 v2 = *(const bf16x8*)(sb + (size_t)s2 * ROWB);
    bf16x8 v3 = *(const bf16x8*)(sb + (size_t)s3 * ROWB);
#pragma unroll
    for (int k = 0; k < 8; ++k)
      acc[k] += ((float)v0[k] + (float)v1[k]) + ((float)v2[k] + (float)v3[k]);
  }
  int base = g8 * 8;
  int rem = deg & 7;
  int rp = rem >> 1;
  for (int u = 0; u < rp; ++u) {
    int r0 = lp[base + 2 * u + half];
    bf16x8 v0 = *(const bf16x8*)(sb + (size_t)r0 * ROWB);
#pragma unroll
    for (int k = 0; k < 8; ++k) acc[k] += (float)v0[k];
  }
  if ((rem & 1) && half == 0) {
    int r0 = lp[deg - 1];
    bf16x8 v0 = *(const bf16x8*)(sb + (size_t)r0 * ROWB);
#pragma unroll
    for (int k = 0; k < 8; ++k) acc[k] += (float)v0[k];
  }

  float inv = 1.0f / (float)(deg > 0 ? deg : 1);
  bf16x8 o;
#pragma unroll
  for (int k = 0; k < 8; ++k) {
    float s = acc[k] + __shfl_down(acc[k], 32);
    o[k] = (__bf16)(s * inv);
  }
  if (half == 0)
    *(bf16x8*)(dstbase + (size_t)i * ROWB + l5 * 16) = o;
}

// ---- direct-load GEMM: out[M,256] = A[M,512] @ Wcat[512,256] + bias -------
// R13: BM=128, 4 waves (2m x 2n), wave tile 64x128. NO LDS, NO barriers:
// per kk each lane loads 4 A-chunks (own rows, HBM-streamed) + 8 B-chunks
// (WtB layout, 4x256B segments, L1/L2-hot) straight into registers, then
// 32 MFMAs. Fragment algebra identical to the R9 LDS path:
//   lane(q=lane>>4, r=lane&15): A[row0+(wm*4+t)*16+r][kk*32+q*8+e],
//                               B[kk*32+q*8+e][wn*128+u*16+r].

template <int OUT_F32>
__global__ __launch_bounds__(256) void gemm_sage(const char* __restrict__ Abase,
                                                 const __bf16* __restrict__ WtB,
                                                 const float* __restrict__ bias,
                                                 char* __restrict__ outbase, int M) {
  const int tid = threadIdx.x;
  const int wave = tid >> 6, lane = tid & 63;
  const int r = lane & 15, q = lane >> 4;
  const int wm = wave >> 1, wn = wave & 1;
  const int row0 = blockIdx.x * 128;

  f32x4 acc[4][8];
#pragma unroll
  for (int t = 0; t < 4; ++t)
#pragma unroll
    for (int u = 0; u < 8; ++u) acc[t][u] = (f32x4)0.f;

  // per-lane A row base pointers (clamped; garbage rows masked at store)
  const char* aptr[4];
#pragma unroll
  for (int t = 0; t < 4; ++t) {
    int rowA = row0 + (wm * 4 + t) * 16 + r;
    rowA = rowA < M ? rowA : M - 1;
    aptr[t] = Abase + (size_t)rowA * ROWB + q * 16;
  }
  // per-lane B base: chunk (q*256 + wn*128 + r), +u*256B, +kk*16384B
  const char* bbase = (const char*)WtB + ((size_t)q * 256 + wn * 128 + r) * 16;

  for (int kk = 0; kk < 16; ++kk) {
    bf16x8 a[4], b[8];
#pragma unroll
    for (int t = 0; t < 4; ++t)
      a[t] = *(const bf16x8*)(aptr[t] + kk * 64);
#pragma unroll
    for (int u = 0; u < 8; ++u)
      b[u] = *(const bf16x8*)(bbase + kk * 16384 + u * 256);
#pragma unroll
    for (int u = 0; u < 8; ++u)
#pragma unroll
      for (int t = 0; t < 4; ++t)
        acc[t][u] = __builtin_amdgcn_mfma_f32_16x16x32_bf16(a[t], b[u], acc[t][u], 0, 0, 0);
  }

  // epilogue. Stores data-depend on all A loads (acc chain), and A rows are
  // block-private -> in-place fp32 overwrite of own rows is safe.
#pragma unroll
  for (int t = 0; t < 4; ++t) {
    int rbase = row0 + wm * 64 + t * 16 + q * 4;
#pragma unroll
    for (int u = 0; u < 8; ++u) {
      int col = wn * 128 + u * 16 + r;
      float bv = bias[col];
#pragma unroll
      for (int j = 0; j < 4; ++j) {
        int row = rbase + j;
        if (row < M) {
          float v = acc[t][u][j] + bv;
          if (OUT_F32)
            *(float*)(outbase + (size_t)row * ROWB + col * 4) = v;
          else
            *(__bf16*)(outbase + (size_t)row * ROWB + 512 + col * 2) = (__bf16)v;
        }
      }
    }
  }
}

// ---- final index gathers --------------------------------------------------

__global__ void gather_out_kernel(const float* __restrict__ x2, const int* __restrict__ drug,
                                  const int* __restrict__ se, float* __restrict__ out,
                                  int nd, int ns) {
  int wave = threadIdx.x >> 6, lane = threadIdx.x & 63;
  int ro = blockIdx.x * 4 + wave;
  if (ro >= nd + ns) return;
  int node = (ro < nd) ? drug[ro] : se[ro - nd];
  float4 v = *(const float4*)(x2 + (size_t)node * 256 + lane * 4);
  *(float4*)(out + (size_t)ro * 256 + lane * 4) = v;
}

// ---------------------------------------------------------------------------

extern "C" void kernel_launch(void* const* d_in, const int* in_sizes, int n_in,
                              void* d_out, int out_size, void* d_ws, size_t ws_size,
                              hipStream_t stream) {
  const float* emb  = (const float*)d_in[0];
  const float* W1l  = (const float*)d_in[1];
  const float* b1l  = (const float*)d_in[2];
  const float* W1r  = (const float*)d_in[3];
  const float* W2l  = (const float*)d_in[4];
  const float* b2l  = (const float*)d_in[5];
  const float* W2r  = (const float*)d_in[6];
  const int* x_idx  = (const int*)d_in[7];
  const int* edge   = (const int*)d_in[8];
  const int* drug   = (const int*)d_in[9];
  const int* se     = (const int*)d_in[10];

  const int N = in_sizes[7];       // 100000
  const int E = in_sizes[8] / 2;   // 1600000
  const int nd = in_sizes[9], ns = in_sizes[10];
  const int* esrc = edge;
  const int* edst = edge + E;
  const int NBUK = (N + 63) >> 6;  // 1563 (<= MAXBUK)
  const int chunk = (E + NPART - 1) / NPART;

  // persistent workspace carve (~110 MB)
  char* ws = (char*)d_ws;
  size_t off = 0;
  char* xA1 = ws;                       off += (size_t)((N + 127) & ~127) * ROWB;
  __bf16* Wt1 = (__bf16*)(ws + off);    off += 512 * 256 * 2;
  __bf16* Wt2 = (__bf16*)(ws + off);    off += 512 * 256 * 2;
  int* cnt  = (int*)(ws + off);         off += ((size_t)N * 4 + 255) & ~(size_t)255;
  int* offs = (int*)(ws + off);         off += ((size_t)N * 4 + 255) & ~(size_t)255;
  int* csr  = (int*)(ws + off);         off += ((size_t)E * 4 + 255) & ~(size_t)255;
  // transient arrays overlay xA1 (all dead before gather_x writes xA1):
  int* ebuf = (int*)xA1;                         // E ints (6.4 MB)
  int* hmat = (int*)(xA1 + (8u << 20));          // NPART*NBUK ints (~1.6 MB)
  int* btot = (int*)(xA1 + (16u << 20));         // NBUK ints
  int* boff = (int*)(xA1 + (16u << 20) + 16384); // NBUK ints

  // d_out carve: [drug nd*256 | se ns*256 | x2 N*256] fp32
  float* outp = (float*)d_out;
  float* x2 = outp + (size_t)(nd + ns) * 256;
  char* scratch2 = (char*)x2;  // rows of 1KB: [mean2 bf16 | x1 bf16] -> x2 fp32

  const int QB = (N + 3) / 4;
  const int GB = (N + 127) / 128;   // gemm grid, BM=128

  prep_w_kernel<<<(2 * 131072) / 256, 256, 0, stream>>>(W1l, W1r, W2l, W2r, Wt1, Wt2);

  // CSR build, deterministic (no global atomics)
  bin_count<<<NPART, 256, 0, stream>>>(edst, hmat, E, chunk, NBUK);
  col_scan<<<NBUK, NPART, 0, stream>>>(hmat, btot, NBUK);
  bucket_scan<<<1, 1024, 0, stream>>>(btot, boff, NBUK);
  part_write<<<NPART, 256, 0, stream>>>(esrc, edst, hmat, boff, ebuf, E, chunk, NBUK);
  hist_csr<<<NBUK, 256, 0, stream>>>(ebuf, boff, btot, cnt, offs, csr, N);

  gather_x_kernel<<<QB, 256, 0, stream>>>(emb, x_idx, xA1 + 512, N);
  // layer 1
  sage_agg<<<QB, 256, 0, stream>>>(xA1 + 512, xA1, csr, cnt, offs, N);
  gemm_sage<0><<<GB, 256, 0, stream>>>(xA1, Wt1, b1l, scratch2, N);
  // layer 2
  sage_agg<<<QB, 256, 0, stream>>>(scratch2 + 512, scratch2, csr, cnt, offs, N);
  gemm_sage<1><<<GB, 256, 0, stream>>>(scratch2, Wt2, b2l, scratch2, N);

  gather_out_kernel<<<(nd + ns + 3) / 4, 256, 0, stream>>>(x2, drug, se, outp, nd, ns);
}

// Round 11
// 632.769 us; speedup vs baseline: 1.2050x; 1.2050x over previous
//
#include <hip/hip_runtime.h>
#include <hip/hip_bf16.h>

// ---------------------------------------------------------------------------
// 2-layer GraphSAGE (mean aggr) on gfx950.
// R14 (this round): revert R13's direct-load gemm (145us vs 82us measured —
// VGPR=148 shows compiler serialized the 12 per-kk register loads; lesson:
// only global_load_lds staging reliably gets loads in flight on this
// compiler). gemm + prep_w restored to the R9-measured forms. Keep hist_csr
// (measured neutral, −1 launch). NEW probe: bin_prep = bin_count + prep_w
// two-role kernel (1280 blocks) — saves a launch and cheaply tests whether
// multi-role kernels correlate with container failures (R10's 26K-block
// mega-kernel never ran; this is the minimal version).
// R9: gemm BM=128 wave-tile 64x128, LDS double-buffered, ~82us each.
// R5-R7: sage_agg at ~3.9 TB/s L2-fill ceiling; FETCH 379 MB ~= 95% of the
// structural minimum for a random graph -> closed.
// CSR build deterministic (R3). Others ~= 242us (R9/R13 invariant).
// ---------------------------------------------------------------------------

typedef __bf16 bf16x8 __attribute__((ext_vector_type(8)));
typedef __bf16 bf16x4 __attribute__((ext_vector_type(4)));
typedef float  f32x4  __attribute__((ext_vector_type(4)));
typedef float  f32x8  __attribute__((ext_vector_type(8)));

#define ROWB 1024   // bytes per A row: 512 bf16 (K = 512 = [mean | x])
#define NPART 256   // partition blocks
#define MAXBUK 2048 // bucket capacity bound (N<=131072)
#define PREPB 1024  // prep_w blocks (2*131072/256)

__device__ __forceinline__ void async_copy16(void* lds_dst, const void* g_src) {
  __builtin_amdgcn_global_load_lds(
      (const __attribute__((address_space(1))) void*)g_src,
      (__attribute__((address_space(3))) void*)lds_dst, 16, 0, 0);
}

// ---- prologue: bin_count + prep_w two-role kernel -------------------------
// blocks [0, NPART):           bin_count (LDS histogram of dst>>6 per chunk)
// blocks [NPART, NPART+PREPB): prep_w    Wt[n][k] = bf16(k<256?Wl[k][n]:Wr[k-256][n])

__global__ void bin_prep(const int* __restrict__ edst, int* __restrict__ hmat,
                         int E, int chunk, int nbuk,
                         const float* __restrict__ W1l, const float* __restrict__ W1r,
                         const float* __restrict__ W2l, const float* __restrict__ W2r,
                         __bf16* __restrict__ Wt1, __bf16* __restrict__ Wt2) {
  __shared__ int lh[MAXBUK];
  int b = blockIdx.x, tid = threadIdx.x;
  if (b < NPART) {
    for (int i = tid; i < nbuk; i += 256) lh[i] = 0;
    __syncthreads();
    int base = b * chunk, end = min(base + chunk, E);
    for (int e = base + tid; e < end; e += 256) atomicAdd(&lh[edst[e] >> 6], 1);
    __syncthreads();
    for (int i = tid; i < nbuk; i += 256) hmat[b * nbuk + i] = lh[i];
  } else {
    int idx = (b - NPART) * 256 + tid;  // 0 .. 2*131072-1
    int which = idx >> 17;
    int j = idx & 131071;
    int n = j >> 9, k = j & 511;
    const float* Wl = which ? W2l : W1l;
    const float* Wr = which ? W2r : W1r;
    float v = (k < 256) ? Wl[k * 256 + n] : Wr[(k - 256) * 256 + n];
    (which ? Wt2 : Wt1)[j] = (__bf16)v;
  }
}

// ---- CSR build (rest of chain) --------------------------------------------

// block b: exclusive scan of hmat[0..NPART-1][b]; btot[b] = total
__global__ void col_scan(int* __restrict__ hmat, int* __restrict__ btot, int nbuk) {
  __shared__ int s[NPART];
  int b = blockIdx.x, t = threadIdx.x;  // NPART threads
  int v = hmat[t * nbuk + b];
  s[t] = v; __syncthreads();
  for (int d = 1; d < NPART; d <<= 1) {
    int add = (t >= d) ? s[t - d] : 0;
    __syncthreads();
    s[t] += add;
    __syncthreads();
  }
  hmat[t * nbuk + b] = s[t] - v;  // exclusive within bucket
  if (t == NPART - 1) btot[b] = s[t];
}

// single block, 1024 threads, nb <= 2048: exclusive scan btot -> boff
__global__ void bucket_scan(const int* __restrict__ btot, int* __restrict__ boff, int nb) {
  __shared__ int s[2048];
  int t = threadIdx.x;
  for (int i = t; i < 2048; i += 1024) s[i] = (i < nb) ? btot[i] : 0;
  __syncthreads();
  for (int d = 1; d < 2048; d <<= 1) {
    int v0 = (t >= d) ? s[t - d] : 0;
    int v1 = (t + 1024 >= d) ? s[t + 1024 - d] : 0;
    __syncthreads();
    s[t] += v0; s[t + 1024] += v1;
    __syncthreads();
  }
  for (int i = t; i < nb; i += 1024) boff[i] = s[i] - btot[i];
}

// block p: write its chunk's edges into disjoint per-bucket windows.
// entry = src | ((dst&63) << 18)   (src < 2^18)
__global__ void part_write(const int* __restrict__ src, const int* __restrict__ dst,
                           const int* __restrict__ hmat, const int* __restrict__ boff,
                           int* __restrict__ ebuf, int E, int chunk, int nbuk) {
  __shared__ int cur[MAXBUK];
  int p = blockIdx.x, tid = threadIdx.x;
  for (int i = tid; i < nbuk; i += 256) cur[i] = hmat[p * nbuk + i] + boff[i];
  __syncthreads();
  int base = p * chunk, end = min(base + chunk, E);
  for (int e = base + tid; e < end; e += 256) {
    int d = dst[e];
    int pos = atomicAdd(&cur[d >> 6], 1);  // LDS atomic, low contention
    ebuf[pos] = src[e] | ((d & 63) << 18);
  }
}

// block b: degree hist + in-bucket exclusive scan -> cnt/offs, then place
// the bucket's edges into csr via LDS cursors (fused; one ebuf pass saved,
// second pass reads the bucket window L2-hot).
__global__ void hist_csr(const int* __restrict__ ebuf, const int* __restrict__ boff,
                         const int* __restrict__ btot, int* __restrict__ cnt,
                         int* __restrict__ offs, int* __restrict__ csr, int N) {
  __shared__ int lh[64];
  __shared__ int cur[64];
  int b = blockIdx.x, tid = threadIdx.x;
  if (tid < 64) lh[tid] = 0;
  __syncthreads();
  int s0 = boff[b], s1 = s0 + btot[b];
  for (int i = s0 + tid; i < s1; i += 256) atomicAdd(&lh[ebuf[i] >> 18], 1);
  __syncthreads();
  if (tid < 64) {  // wave 0: 64-wide inclusive shfl scan
    int v = lh[tid];
    int x = v;
#pragma unroll
    for (int d = 1; d < 64; d <<= 1) {
      int y = __shfl_up(x, d);
      if (tid >= d) x += y;
    }
    int o = s0 + x - v;  // exclusive start
    cur[tid] = o;
    int node = b * 64 + tid;
    if (node < N) { cnt[node] = v; offs[node] = o; }
  }
  __syncthreads();
  for (int i = s0 + tid; i < s1; i += 256) {
    int e = ebuf[i];
    int p = atomicAdd(&cur[e >> 18], 1);
    csr[p] = e & 0x3FFFF;
  }
}

// ---- feature prep ---------------------------------------------------------

// x-half gather: xbase points at (row stride ROWB) destination of the x slot
__global__ void gather_x_kernel(const float* __restrict__ emb, const int* __restrict__ x_idx,
                                char* __restrict__ xbase, int N) {
  int wave = threadIdx.x >> 6, lane = threadIdx.x & 63;
  int i = blockIdx.x * 4 + wave;
  if (i >= N) return;
  int s = x_idx[i];
  float4 v = *(const float4*)(emb + (size_t)s * 256 + lane * 4);
  bf16x4 o = { (__bf16)v.x, (__bf16)v.y, (__bf16)v.z, (__bf16)v.w };
  *(bf16x4*)(xbase + (size_t)i * ROWB + lane * 8) = o;
}

// ---- mean aggregation -----------------------------------------------------
// Wave per node; 2x32-lane halves read DIFFERENT src rows at 16B/lane
// (dwordx4). 8 edges/iter, 4 loads in flight. shfl_down(32) combine.
// Perf-equal across MLP 1/2/4 variants -> L2-fill throughput ceiling.

__global__ void sage_agg(const char* __restrict__ srcbase,  // row r: srcbase + r*ROWB, 256 bf16
                         char* __restrict__ dstbase,        // node i: dstbase + i*ROWB, 256 bf16
                         const int* __restrict__ csr, const int* __restrict__ cnt,
                         const int* __restrict__ offs, int N) {
  int wave = threadIdx.x >> 6, lane = threadIdx.x & 63;
  int i = blockIdx.x * 4 + wave;
  if (i >= N) return;
  int deg = cnt[i];
  const int* lp = csr + offs[i];
  int half = lane >> 5, l5 = lane & 31;
  const char* sb = srcbase + l5 * 16;

  f32x8 acc = (f32x8)0.f;
  int g8 = deg >> 3;
  for (int t = 0; t < g8; ++t) {  // 8 edges per iteration (4 per half)
    const int* p = lp + t * 8 + half;
    int s0 = p[0], s1 = p[2], s2 = p[4], s3 = p[6];
    bf16x8 v0 = *(const bf16x8*)(sb + (size_t)s0 * ROWB);
    bf16x8 v1 = *(const bf16x8*)(sb + (size_t)s1 * ROWB);
    bf16x8 v2 = *(const bf16x8*)(sb + (size_t)s2 * ROWB);
    bf16x8 v3 = *(const bf16x8*)(sb + (size_t)s3 * ROWB);
#pragma unroll
    for (int k = 0; k < 8; ++k)
      acc[k] += ((float)v0[k] + (float)v1[k]) + ((float)v2[k] + (float)v3[k]);
  }
  int base = g8 * 8;
  int rem = deg & 7;
  int rp = rem >> 1;
  for (int u = 0; u < rp; ++u) {
    int r0 = lp[base + 2 * u + half];
    bf16x8 v0 = *(const bf16x8*)(sb + (size_t)r0 * ROWB);
#pragma unroll
    for (int k = 0; k < 8; ++k) acc[k] += (float)v0[k];
  }
  if ((rem & 1) && half == 0) {
    int r0 = lp[deg - 1];
    bf16x8 v0 = *(const bf16x8*)(sb + (size_t)r0 * ROWB);
#pragma unroll
    for (int k = 0; k < 8; ++k) acc[k] += (float)v0[k];
  }

  float inv = 1.0f / (float)(deg > 0 ? deg : 1);
  bf16x8 o;
#pragma unroll
  for (int k = 0; k < 8; ++k) {
    float s = acc[k] + __shfl_down(acc[k], 32);
    o[k] = (__bf16)(s * inv);
  }
  if (half == 0)
    *(bf16x8*)(dstbase + (size_t)i * ROWB + l5 * 16) = o;
}

// ---- fused GEMM: out[M,256] = A[M,512] @ Wcat[512,256] + bias -------------
// R9 form (measured ~82us): BM=128, BN=256, BK=32, 256 threads = 4 waves
// (2m x 2n), wave tile 64x128, LDS double-buffered via global_load_lds.

template <int OUT_F32>
__global__ __launch_bounds__(256) void gemm_sage(const char* __restrict__ Abase,
                                                 const __bf16* __restrict__ Wt,
                                                 const float* __restrict__ bias,
                                                 char* __restrict__ outbase, int M) {
  __shared__ __align__(16) char lds[49152];  // 2 bufs x (A 8KB + B 16KB)
  const int tid = threadIdx.x;
  const int wave = tid >> 6, lane = tid & 63;
  const int r = lane & 15, q = lane >> 4;
  const int wm = wave >> 1, wn = wave & 1;
  const int row0 = blockIdx.x * 128;

  f32x4 acc[4][8];
#pragma unroll
  for (int t = 0; t < 4; ++t)
#pragma unroll
    for (int u = 0; u < 8; ++u) acc[t][u] = (f32x4)0.f;

  auto stage = [&](int kk, int buf) {
    char* lbase = lds + buf * 24576;
    // A: 8 x 1KB chunks (16 rows x 32 cols each); each thread issues 2
#pragma unroll
    for (int i = 0; i < 2; ++i) {
      int h = wave * 2 + i;  // 0..7
      int rowA = row0 + h * 16 + r;
      rowA = rowA < M ? rowA : M - 1;  // clamp: garbage rows masked at store
      async_copy16(lbase + h * 1024 + lane * 16,
                   Abase + (size_t)rowA * ROWB + (size_t)(kk * 32 + q * 8) * 2);
    }
    // B: 16 x 1KB chunks (16 cols x 32 k each); each thread issues 4
#pragma unroll
    for (int i = 0; i < 4; ++i) {
      int h = wave * 4 + i;  // 0..15
      async_copy16(lbase + 8192 + h * 1024 + lane * 16,
                   (const char*)Wt + ((size_t)(h * 16 + r) * 512 + kk * 32 + q * 8) * 2);
    }
  };

  stage(0, 0);
  for (int kk = 0; kk < 16; ++kk) {
    __syncthreads();  // compiler drains vmcnt before s_barrier -> staging done
    if (kk < 15) stage(kk + 1, (kk + 1) & 1);
    const char* lbase = lds + (kk & 1) * 24576;
    bf16x8 a[4];
#pragma unroll
    for (int t = 0; t < 4; ++t)
      a[t] = *(const bf16x8*)(lbase + (wm * 4 + t) * 1024 + lane * 16);
#pragma unroll
    for (int u = 0; u < 8; ++u) {
      bf16x8 b = *(const bf16x8*)(lbase + 8192 + (wn * 8 + u) * 1024 + lane * 16);
#pragma unroll
      for (int t = 0; t < 4; ++t)
        acc[t][u] = __builtin_amdgcn_mfma_f32_16x16x32_bf16(a[t], b, acc[t][u], 0, 0, 0);
    }
  }

  // epilogue. All global A reads drained at the kk=15 barrier, so in-place
  // fp32 overwrite of this block's own rows (sole owner, BN=256) is safe.
#pragma unroll
  for (int t = 0; t < 4; ++t) {
    int rbase = row0 + wm * 64 + t * 16 + q * 4;
#pragma unroll
    for (int u = 0; u < 8; ++u) {
      int col = wn * 128 + u * 16 + r;
      float bv = bias[col];
#pragma unroll
      for (int j = 0; j < 4; ++j) {
        int row = rbase + j;
        if (row < M) {
          float v = acc[t][u][j] + bv;
          if (OUT_F32)
            *(float*)(outbase + (size_t)row * ROWB + col * 4) = v;
          else
            *(__bf16*)(outbase + (size_t)row * ROWB + 512 + col * 2) = (__bf16)v;
        }
      }
    }
  }
}

// ---- final index gathers --------------------------------------------------

__global__ void gather_out_kernel(const float* __restrict__ x2, const int* __restrict__ drug,
                                  const int* __restrict__ se, float* __restrict__ out,
                                  int nd, int ns) {
  int wave = threadIdx.x >> 6, lane = threadIdx.x & 63;
  int ro = blockIdx.x * 4 + wave;
  if (ro >= nd + ns) return;
  int node = (ro < nd) ? drug[ro] : se[ro - nd];
  float4 v = *(const float4*)(x2 + (size_t)node * 256 + lane * 4);
  *(float4*)(out + (size_t)ro * 256 + lane * 4) = v;
}

// ---------------------------------------------------------------------------

extern "C" void kernel_launch(void* const* d_in, const int* in_sizes, int n_in,
                              void* d_out, int out_size, void* d_ws, size_t ws_size,
                              hipStream_t stream) {
  const float* emb  = (const float*)d_in[0];
  const float* W1l  = (const float*)d_in[1];
  const float* b1l  = (const float*)d_in[2];
  const float* W1r  = (const float*)d_in[3];
  const float* W2l  = (const float*)d_in[4];
  const float* b2l  = (const float*)d_in[5];
  const float* W2r  = (const float*)d_in[6];
  const int* x_idx  = (const int*)d_in[7];
  const int* edge   = (const int*)d_in[8];
  const int* drug   = (const int*)d_in[9];
  const int* se     = (const int*)d_in[10];

  const int N = in_sizes[7];       // 100000
  const int E = in_sizes[8] / 2;   // 1600000
  const int nd = in_sizes[9], ns = in_sizes[10];
  const int* esrc = edge;
  const int* edst = edge + E;
  const int NBUK = (N + 63) >> 6;  // 1563 (<= MAXBUK)
  const int chunk = (E + NPART - 1) / NPART;

  // persistent workspace carve (~110 MB)
  char* ws = (char*)d_ws;
  size_t off = 0;
  char* xA1 = ws;                       off += (size_t)((N + 127) & ~127) * ROWB;
  __bf16* Wt1 = (__bf16*)(ws + off);    off += 512 * 256 * 2;
  __bf16* Wt2 = (__bf16*)(ws + off);    off += 512 * 256 * 2;
  int* cnt  = (int*)(ws + off);         off += ((size_t)N * 4 + 255) & ~(size_t)255;
  int* offs = (int*)(ws + off);         off += ((size_t)N * 4 + 255) & ~(size_t)255;
  int* csr  = (int*)(ws + off);         off += ((size_t)E * 4 + 255) & ~(size_t)255;
  // transient arrays overlay xA1 (all dead before gather_x writes xA1):
  int* ebuf = (int*)xA1;                         // E ints (6.4 MB)
  int* hmat = (int*)(xA1 + (8u << 20));          // NPART*NBUK ints (~1.6 MB)
  int* btot = (int*)(xA1 + (16u << 20));         // NBUK ints
  int* boff = (int*)(xA1 + (16u << 20) + 16384); // NBUK ints

  // d_out carve: [drug nd*256 | se ns*256 | x2 N*256] fp32
  float* outp = (float*)d_out;
  float* x2 = outp + (size_t)(nd + ns) * 256;
  char* scratch2 = (char*)x2;  // rows of 1KB: [mean2 bf16 | x1 bf16] -> x2 fp32

  const int QB = (N + 3) / 4;
  const int GB = (N + 127) / 128;   // gemm grid, BM=128

  // prologue: bin_count + prep_w in one two-role dispatch
  bin_prep<<<NPART + PREPB, 256, 0, stream>>>(
      edst, hmat, E, chunk, NBUK, W1l, W1r, W2l, W2r, Wt1, Wt2);

  col_scan<<<NBUK, NPART, 0, stream>>>(hmat, btot, NBUK);
  bucket_scan<<<1, 1024, 0, stream>>>(btot, boff, NBUK);
  part_write<<<NPART, 256, 0, stream>>>(esrc, edst, hmat, boff, ebuf, E, chunk, NBUK);
  hist_csr<<<NBUK, 256, 0, stream>>>(ebuf, boff, btot, cnt, offs, csr, N);

  gather_x_kernel<<<QB, 256, 0, stream>>>(emb, x_idx, xA1 + 512, N);
  // layer 1
  sage_agg<<<QB, 256, 0, stream>>>(xA1 + 512, xA1, csr, cnt, offs, N);
  gemm_sage<0><<<GB, 256, 0, stream>>>(xA1, Wt1, b1l, scratch2, N);
  // layer 2
  sage_agg<<<QB, 256, 0, stream>>>(scratch2 + 512, scratch2, csr, cnt, offs, N);
  gemm_sage<1><<<GB, 256, 0, stream>>>(scratch2, Wt2, b2l, scratch2, N);

  gather_out_kernel<<<(nd + ns + 3) / 4, 256, 0, stream>>>(x2, drug, se, outp, nd, ns);
}